// Round 3
// baseline (492.589 us; speedup 1.0000x reference)
//
#include <hip/hip_runtime.h>

#define G    128          // 4*HID
#define HID  32
#define EMB  16
#define BB   256
#define TT   2048
#define VOC  5000

#define LOG2E      1.44269504088896340736f
#define TWOLOG2E   2.88539008177792681472f

typedef float v2f __attribute__((ext_vector_type(2)));
typedef __attribute__((ext_vector_type(8))) short short8;   // 8 bf16 (4 VGPRs)
typedef __attribute__((ext_vector_type(4))) float f32x4;    // MFMA C/D frag

__device__ __forceinline__ float bf2f(unsigned short u) {
    return __uint_as_float(((unsigned)u) << 16);
}
__device__ __forceinline__ unsigned short f2bf(float f) {
    unsigned x = __float_as_uint(f);
    return (unsigned short)((x + 0x7FFFu + ((x >> 16) & 1u)) >> 16);  // RNE
}
// legacy math for fallback kernel (natural units)
__device__ __forceinline__ float sigm(float x) {
    const float e = __expf(-x);
    return __builtin_amdgcn_rcpf(1.f + e);
}
__device__ __forceinline__ float tanh_f(float x) {
    const float e = __expf(-2.f * x);
    return (1.f - e) * __builtin_amdgcn_rcpf(1.f + e);
}
__device__ __forceinline__ float rdlf(float v, int k) {
    return __int_as_float(__builtin_amdgcn_readlane(__float_as_int(v), k));
}
// DPP lane exchange (pure VALU; no LDS pipe)
template <int CTRL>
__device__ __forceinline__ unsigned dppq_u(unsigned v) {
    return (unsigned)__builtin_amdgcn_update_dpp(0, (int)v, CTRL, 0xF, 0xF, true);
}
template <int CTRL>
__device__ __forceinline__ float dppq_f(float v) {
    return __uint_as_float(dppq_u<CTRL>(__float_as_uint(v)));
}
#define DPP_XOR2   0x4E    // quad_perm [2,3,0,1] : partner unit (lane^2)
#define DPP_BODD   0xF5    // quad_perm [1,1,3,3] : broadcast odd lane of pair
#define DPP_BEVN   0xA0    // quad_perm [0,0,2,2] : broadcast even lane of pair
#define DPP_HMIRR  0x141   // row_half_mirror: quad p -> p^1
#define DPP_ROR8   0x128   // row rotate 8:    quad p -> p^2
#define DPP_MIRR   0x140   // row_mirror:      quad p -> p^3

// dup-pair gate-column mapping: lane l -> first col ca, second col ca+64
__device__ __host__ __forceinline__ int col_a(int l) {
    return (l >> 1) + 32 * (l & 1);
}

// ---------------------------------------------------------------------------
// Inline dtype detector (true -> fp32 buffers, false -> bf16 buffers).
// Wave-parallel; every block computes it redundantly (1 load + ballot).
// ---------------------------------------------------------------------------
__device__ __forceinline__ bool detect_f32(const unsigned* __restrict__ bias_w,
                                           int lane) {
    const unsigned u  = bias_w[lane];
    const unsigned lo = u & 0xFFFFu;
    const float vlo = __uint_as_float(lo << 16);
    const float vhi = __uint_as_float(u & 0xFFFF0000u);
    const bool nz_even = (lo != 0u);
    const bool big = !(fabsf(vlo) < 1e6f) || !(fabsf(vhi) < 1e6f);
    const unsigned long long nz = __ballot(nz_even);
    const unsigned long long bg = __ballot(big);
    return (nz == 0ull || bg != 0ull);
}

// ---------------------------------------------------------------------------
// Token z-table, dup-pair permuted, prescaled by log2(e), g-columns by 2x,
// and i-columns (even-lane a-entries) biased by +1 so the scan's rcp gives
// 2*sigma directly:
//   ZK[v][2l]   = log2e * z_x[col_a(l)] + (l even ? 1 : 0)
//   ZK[v][2l+1] = log2e * s * z_x[col_a(l)+64], s=2 for even l (g), 1 (o)
// 8 vocab rows per block: weight regs loaded once, reused 8x.
// ---------------------------------------------------------------------------
#define ZK_RPB 8
__global__ __launch_bounds__(64) void zk_kernel(
    const void* __restrict__ emb, const void* __restrict__ Wk,
    const void* __restrict__ bias, float* __restrict__ ZK)
{
    const int l  = threadIdx.x;
    const int v0 = blockIdx.x * ZK_RPB;
    const bool f32 = detect_f32((const unsigned*)bias, l);
    const int ca = col_a(l), cb = ca + 64;
    const float ba_add = ((l & 1) == 0) ? 1.f : 0.f;     // i-col exp-fold bias
    const float sb = ((l & 1) == 0) ? 2.f * LOG2E : LOG2E;

    float wa[EMB], wb[EMB], ba, bb;
    if (f32) {
        const float* W = (const float*)Wk;
        const float* B = (const float*)bias;
#pragma unroll
        for (int e = 0; e < EMB; ++e) { wa[e] = W[e * G + ca]; wb[e] = W[e * G + cb]; }
        ba = B[ca]; bb = B[cb];
    } else {
        const unsigned short* W = (const unsigned short*)Wk;
        const unsigned short* B = (const unsigned short*)bias;
#pragma unroll
        for (int e = 0; e < EMB; ++e) { wa[e] = bf2f(W[e * G + ca]); wb[e] = bf2f(W[e * G + cb]); }
        ba = bf2f(B[ca]); bb = bf2f(B[cb]);
    }

#pragma unroll
    for (int r = 0; r < ZK_RPB; ++r) {
        const int v = v0 + r;
        float x[EMB];
        if (f32) {
            const float* E = (const float*)emb + (size_t)v * EMB;
#pragma unroll
            for (int e = 0; e < EMB; ++e) x[e] = E[e];
        } else {
            const unsigned short* E = (const unsigned short*)emb + (size_t)v * EMB;
#pragma unroll
            for (int e = 0; e < EMB; ++e) x[e] = bf2f(E[e]);
        }
        float za = ba, zb = bb;
#pragma unroll
        for (int e = 0; e < EMB; ++e) {
            za = fmaf(x[e], wa[e], za);
            zb = fmaf(x[e], wb[e], zb);
        }
        v2f o2;
        o2.x = fmaf(za, LOG2E, ba_add);
        o2.y = zb * sb;
        *(v2f*)(ZK + (size_t)v * G + 2 * l) = o2;
    }
}

// ---------------------------------------------------------------------------
// Scan (dup-pair + MFMA): lane l owns hidden unit j=l>>1, half=l&1.
// h->h chain per step: pack (add, dpp, var-sel perm, 3x dpp) -> 8 MFMA with
// z folded into the C operand -> 2 cndmask sel -> exp2 -> add -> rcp
// (one rcp = 2i on even lanes, f on odd lanes) -> q mul -> dpp-add cN
// (cS = -2log2e*c scaled domain) -> exp2 -> add -> rcp -> fma hN -> mask.
// ZERO DS instructions in the recurrence chain.
// ---------------------------------------------------------------------------
template <bool F32OUT>
__device__ __forceinline__ void scan_zk_loop(
    const int* __restrict__ trow, const float* __restrict__ ZK,
    void* __restrict__ orow, const short8 (&Bf)[8], int lane)
{
    const bool  h0  = (lane & 1) == 0;          // half 0: (i,g); half 1: (f,o)
    const float Kc  = h0 ? 0.5f : 1.0f;         // rcp add-const for a-side
    const int   oj  = lane >> 1;                // my hidden unit
    const int   g4  = (lane >> 4) & 3;          // which MFMA holds my column
    const bool  u_odd = (lane >> 1) & 1;        // my unit index parity
    const unsigned psel = u_odd ? 0x03020706u : 0x07060302u;  // v_perm selector
    const int   lm  = lane & 15;

    float h = 0.f, cS = 0.f;                    // cS = -2log2e * c

    // ---- tokens as scalars: one coalesced vector load per 16-chunk,
    //      extracted to SGPRs via readlane ----
    int tva = trow[lm];           // chunk 0
    int tvb = trow[16 + lm];      // chunk 1
    int tc[16], tn[16];
#pragma unroll
    for (int p = 0; p < 16; ++p) tc[p] = __builtin_amdgcn_readlane(tva, p);
#pragma unroll
    for (int p = 0; p < 16; ++p) tn[p] = __builtin_amdgcn_readlane(tvb, p);

    // ---- ZK prefetch ring, distance 8 ----
    v2f pz[8];
#pragma unroll
    for (int d = 0; d < 8; ++d)
        pz[d] = *(const v2f*)(ZK + (size_t)tc[d] * G + 2 * lane);

    for (int cc = 0; cc < TT / 16; ++cc) {
        const int base = cc * 16;
        // issue chunk cc+2 token vector load early (clamped at tail)
        const int nxtc = (cc + 2 < TT / 16) ? (cc + 2) : (TT / 16 - 1);
        const int tvc = trow[nxtc * 16 + lm];
#pragma unroll
        for (int u = 0; u < 16; ++u) {
            const int t = base + u;
            const v2f z = pz[u & 7];
            {   // prefetch z for t+8 (scalar token -> saddr-form load)
                const int ptok = (u + 8 < 16) ? tc[u + 8] : tn[u - 8];
                pz[u & 7] = *(const v2f*)(ZK + (size_t)ptok * G + 2 * lane);
            }

            // ---- A-frag pack: round, partner via DPP xor2, variable-sel
            //      v_perm, then 3 static DPP gathers (slot q = pair(p^q);
            //      compensated in B-frag k-permutation) ----
            const unsigned rh  = __float_as_uint(h) + 0x8000u;   // round-half-up
            const unsigned prt = dppq_u<DPP_XOR2>(rh);           // partner unit
            const unsigned pair = __builtin_amdgcn_perm(prt, rh, psel);
            const unsigned q1 = dppq_u<DPP_HMIRR>(pair);         // pair(p^1)
            const unsigned q2 = dppq_u<DPP_ROR8 >(pair);         // pair(p^2)
            const unsigned q3 = dppq_u<DPP_MIRR >(pair);         // pair(p^3)
            union { unsigned u4[4]; short8 s8; } au;
            au.u4[0] = pair; au.u4[1] = q1; au.u4[2] = q2; au.u4[3] = q3;
            const short8 Af = au.s8;

            // ---- 8 MFMAs, z folded into C (rows we don't read get junk) ----
            const f32x4 Ca = {z.x, z.x, z.x, z.x};
            const f32x4 Cb = {z.y, z.y, z.y, z.y};
            f32x4 d0 = __builtin_amdgcn_mfma_f32_16x16x32_bf16(Af, Bf[0], Ca, 0, 0, 0);
            f32x4 d1 = __builtin_amdgcn_mfma_f32_16x16x32_bf16(Af, Bf[1], Ca, 0, 0, 0);
            f32x4 d2 = __builtin_amdgcn_mfma_f32_16x16x32_bf16(Af, Bf[2], Ca, 0, 0, 0);
            f32x4 d3 = __builtin_amdgcn_mfma_f32_16x16x32_bf16(Af, Bf[3], Ca, 0, 0, 0);
            f32x4 d4 = __builtin_amdgcn_mfma_f32_16x16x32_bf16(Af, Bf[4], Cb, 0, 0, 0);
            f32x4 d5 = __builtin_amdgcn_mfma_f32_16x16x32_bf16(Af, Bf[5], Cb, 0, 0, 0);
            f32x4 d6 = __builtin_amdgcn_mfma_f32_16x16x32_bf16(Af, Bf[6], Cb, 0, 0, 0);
            f32x4 d7 = __builtin_amdgcn_mfma_f32_16x16x32_bf16(Af, Bf[7], Cb, 0, 0, 0);

            // my columns: a-side pre-activation from d[g4], b-side d[4+g4]
            const float mvb = (g4 < 2) ? (g4 == 0 ? d4.x : d5.x)
                                       : (g4 == 2 ? d6.x : d7.x);
            const float mva = (g4 < 2) ? (g4 == 0 ? d0.x : d1.x)
                                       : (g4 == 2 ? d2.x : d3.x);

            // a-side: even lanes mva = log2e*z_i + 1 -> r1 = 2*sigma(z_i) = 2i
            //         odd lanes  mva = log2e*z_f     -> r1 = sigma(z_f) = f
            const float exa = __builtin_amdgcn_exp2f(-mva);
            const float exb = __builtin_amdgcn_exp2f(-mvb);
            const float r1  = __builtin_amdgcn_rcpf(exa + Kc);
            const float s2  = __builtin_amdgcn_rcpf(exb + 1.f);   // sig(2zg)|o
            // cS-domain i*g: q = 2i * (-2log2e)*(s2-0.5); s2p runs || to r1
            const float s2p = fmaf(s2, -TWOLOG2E, LOG2E);
            const float q   = r1 * s2p;
            // cN = f*cS + bcast_even(q)   (DPP-fusable mul/add forms)
            const float fc  = dppq_f<DPP_BODD>(r1) * cS;
            const float cN  = dppq_f<DPP_BEVN>(q) + fc;
            const float oG  = dppq_f<DPP_BODD>(s2);               // o

            // h = o*tanh(c) = 2o*rcp(1+e^{-2c}) - o ; e^{-2c} = exp2(cS)
            const float exh = __builtin_amdgcn_exp2f(cN);
            const float rr  = __builtin_amdgcn_rcpf(exh + 1.f);
            const float oo  = oG + oG;                            // off-chain
            const float hN  = fmaf(oo, rr, -oG);

            const bool m = tc[u] != 0;                  // scalar token
            cS = m ? cN : cS;
            h  = m ? hN : h;

            const int oi = t * HID + oj;     // pair lanes: same addr+data
            if (F32OUT) __builtin_nontemporal_store(h, (float*)orow + oi);
            else        __builtin_nontemporal_store(f2bf(h), (unsigned short*)orow + oi);
        }
        // rotate token chunks (SALU), extract prefetched chunk cc+2
#pragma unroll
        for (int p = 0; p < 16; ++p) tc[p] = tn[p];
#pragma unroll
        for (int p = 0; p < 16; ++p) tn[p] = __builtin_amdgcn_readlane(tvc, p);
    }
}

__global__ __launch_bounds__(64) void scan_zk_kernel(
    const int* __restrict__ tokens, const float* __restrict__ ZK,
    const void* __restrict__ Wr, const void* __restrict__ bias,
    void* __restrict__ out)
{
    const int lane = threadIdx.x, b = blockIdx.x;
    const bool f32 = detect_f32((const unsigned*)bias, lane);

    // B-frags: MFMA q<4 -> first-gate cols ca(16q+n); q>=4 -> cb(16(q-4)+n).
    // Lane holds B[k=(lane>>4)*8+j][n=lane&15], k XOR-permuted per MFMA
    // (j ^ (q<<1)) to absorb the DPP all-gather's pair(p^q) layout; scaled by
    // log2e, and additionally by 2 for g-columns (p>=4, even n).
    short8 Bf[8];
    const int n  = lane & 15;
    const int k0 = (lane >> 4) * 8;
#pragma unroll
    for (int p = 0; p < 8; ++p) {
        const int ell = 16 * (p & 3) + n;
        const int col = (p < 4) ? col_a(ell) : (col_a(ell) + 64);
        const int jx  = (p & 3) << 1;         // k-pair XOR permutation
        const float sc = (p >= 4 && (n & 1) == 0) ? 2.f * LOG2E : LOG2E;
        short el[8];
        if (f32) {
            const float* W = (const float*)Wr;
#pragma unroll
            for (int j = 0; j < 8; ++j)
                el[j] = (short)f2bf(W[(k0 + (j ^ jx)) * G + col] * sc);
        } else {
            const unsigned short* W = (const unsigned short*)Wr;
#pragma unroll
            for (int j = 0; j < 8; ++j)
                el[j] = (short)f2bf(bf2f(W[(k0 + (j ^ jx)) * G + col]) * sc);
        }
        short8 s;
#pragma unroll
        for (int j = 0; j < 8; ++j) s[j] = el[j];
        Bf[p] = s;
    }

    const int* trow = tokens + (size_t)b * TT;
    if (f32) scan_zk_loop<true >(trow, ZK, (char*)out + (size_t)b * TT * HID * 4, Bf, lane);
    else     scan_zk_loop<false>(trow, ZK, (char*)out + (size_t)b * TT * HID * 2, Bf, lane);
}

// ---------------------------------------------------------------------------
// Fallback (workspace too small): proven R2/R3 fused kernel (natural units).
// ---------------------------------------------------------------------------
template <bool F32>
__device__ __forceinline__ void row_load(const void* emb, int tok, uint4* r) {
    if (F32) { const uint4* p = (const uint4*)((const float*)emb + (size_t)tok*EMB);
               r[0]=p[0]; r[1]=p[1]; r[2]=p[2]; r[3]=p[3]; }
    else     { const uint4* p = (const uint4*)((const unsigned short*)emb + (size_t)tok*EMB);
               r[0]=p[0]; r[1]=p[1]; }
}
template <bool F32>
__device__ __forceinline__ void row_unpack(const uint4* r, float* x) {
    if (F32) {
        const unsigned w[16] = {r[0].x,r[0].y,r[0].z,r[0].w, r[1].x,r[1].y,r[1].z,r[1].w,
                                r[2].x,r[2].y,r[2].z,r[2].w, r[3].x,r[3].y,r[3].z,r[3].w};
#pragma unroll
        for (int e = 0; e < 16; ++e) x[e] = __uint_as_float(w[e]);
    } else {
        const unsigned w[8] = {r[0].x,r[0].y,r[0].z,r[0].w, r[1].x,r[1].y,r[1].z,r[1].w};
#pragma unroll
        for (int q = 0; q < 8; ++q) {
            x[2*q]   = __uint_as_float(w[q] << 16);
            x[2*q+1] = __uint_as_float(w[q] & 0xFFFF0000u);
        }
    }
}

template <bool F32>
__device__ __forceinline__ void scan_fused_loop(
    const int* __restrict__ trow, const void* __restrict__ emb, void* orow,
    const float (&wka)[EMB], const float (&wkb)[EMB],
    const float (&wra)[HID], const float (&wrb)[HID],
    float za0, float zb0, const int* tl, int lane)
{
    const bool  lo  = lane < HID;
    const float zsc = lo ? 2.f : 1.f, gm = lo ? 2.f : 1.f, ga = lo ? -1.f : 0.f;
    float h = 0.f, c = 0.f;
    uint4 praw[2][4];
    row_load<F32>(emb, trow[0], praw[0]);
    row_load<F32>(emb, trow[1], praw[1]);

    for (int tt = 0; tt < TT; tt += 2) {
#pragma unroll
        for (int u = 0; u < 2; ++u) {
            const int t = tt + u;
            float x[EMB];
            row_unpack<F32>(praw[u], x);
            int tn = t + 2; tn = tn > TT - 1 ? TT - 1 : tn;
            row_load<F32>(emb, tl[tn], praw[u]);
            float za = za0, zb = zb0;
#pragma unroll
            for (int e = 0; e < EMB; ++e) { za = fmaf(x[e], wka[e], za); zb = fmaf(x[e], wkb[e], zb); }
#pragma unroll
            for (int k = 0; k < HID; ++k) {
                const float hk = rdlf(h, k);
                za = fmaf(hk, wra[k], za);
                zb = fmaf(hk, wrb[k], zb);
            }
            const float a1 = sigm(za);
            const float s2 = sigm(zb * zsc);
            const float a2 = fmaf(s2, gm, ga);
            const float x1 = __shfl_xor(a1, 32);
            const float x2 = __shfl_xor(a2, 32);
            const float iV = lo ? a1 : x1, fV = lo ? x1 : a1;
            const float gV = lo ? a2 : x2, oV = lo ? x2 : a2;
            const float cN = fmaf(fV, c, iV * gV);
            const float hN = oV * tanh_f(cN);
            const bool  m  = tl[t] != 0;
            c = m ? cN : c;
            h = m ? hN : h;
            const int oi = t * HID + (lane & (HID - 1));
            if (F32) ((float*)orow)[oi] = h;
            else     ((unsigned short*)orow)[oi] = f2bf(h);
        }
    }
}

__global__ __launch_bounds__(64) void scan_fused_kernel(
    const int* __restrict__ tokens, const void* __restrict__ emb,
    const void* __restrict__ Wk, const void* __restrict__ Wr,
    const void* __restrict__ bias, void* __restrict__ out)
{
    __shared__ int tl[TT];
    const int lane = threadIdx.x, b = blockIdx.x;
    const bool f32 = detect_f32((const unsigned*)bias, lane);
    const int* trow = tokens + (size_t)b * TT;
    for (int t = lane; t < TT; t += 64) tl[t] = trow[t];

    float wka[EMB], wkb[EMB], wra[HID], wrb[HID], za0, zb0;
    if (f32) {
        const float* WK = (const float*)Wk; const float* WR = (const float*)Wr;
        const float* B  = (const float*)bias;
#pragma unroll
        for (int e = 0; e < EMB; ++e) { wka[e] = WK[e*G + lane]; wkb[e] = WK[e*G + lane + 64]; }
#pragma unroll
        for (int k = 0; k < HID; ++k) { wra[k] = WR[k*G + lane]; wrb[k] = WR[k*G + lane + 64]; }
        za0 = B[lane]; zb0 = B[lane + 64];
    } else {
        const unsigned short* WK = (const unsigned short*)Wk;
        const unsigned short* WR = (const unsigned short*)Wr;
        const unsigned short* B  = (const unsigned short*)bias;
#pragma unroll
        for (int e = 0; e < EMB; ++e) { wka[e] = bf2f(WK[e*G + lane]); wkb[e] = bf2f(WK[e*G + lane + 64]); }
#pragma unroll
        for (int k = 0; k < HID; ++k) { wra[k] = bf2f(WR[k*G + lane]); wrb[k] = bf2f(WR[k*G + lane + 64]); }
        za0 = bf2f(B[lane]); zb0 = bf2f(B[lane + 64]);
    }
    __syncthreads();

    if (f32) scan_fused_loop<true >(trow, emb, (char*)out + (size_t)b*TT*HID*4,
                                    wka, wkb, wra, wrb, za0, zb0, tl, lane);
    else     scan_fused_loop<false>(trow, emb, (char*)out + (size_t)b*TT*HID*2,
                                    wka, wkb, wra, wrb, za0, zb0, tl, lane);
}

// ---------------------------------------------------------------------------
extern "C" void kernel_launch(void* const* d_in, const int* in_sizes, int n_in,
                              void* d_out, int out_size, void* d_ws, size_t ws_size,
                              hipStream_t stream) {
    const int*  tokens = (const int*)d_in[0];
    const void* emb    = d_in[1];
    const void* Wk     = d_in[2];
    const void* Wr     = d_in[3];
    const void* bias   = d_in[4];

    const size_t zk_off   = 256;
    const size_t zk_bytes = (size_t)VOC * G * sizeof(float);   // 2.56 MB

    if (ws_size >= zk_off + zk_bytes) {
        float* ZK = (float*)((char*)d_ws + zk_off);
        zk_kernel<<<VOC / ZK_RPB, 64, 0, stream>>>(emb, Wk, bias, ZK);
        scan_zk_kernel<<<BB, 64, 0, stream>>>(tokens, ZK, Wr, bias, d_out);
    } else {
        scan_fused_kernel<<<BB, 64, 0, stream>>>(tokens, emb, Wk, Wr, bias, d_out);
    }
}

// Round 4
// 448.606 us; speedup vs baseline: 1.0980x; 1.0980x over previous
//
#include <hip/hip_runtime.h>

#define G    128          // 4*HID
#define HID  32
#define EMB  16
#define BB   256
#define TT   2048
#define VOC  5000

#define LOG2E      1.44269504088896340736f
#define TWOLOG2E   2.88539008177792681472f

typedef float v2f __attribute__((ext_vector_type(2)));
typedef __attribute__((ext_vector_type(8))) short short8;   // 8 bf16 (4 VGPRs)
typedef __attribute__((ext_vector_type(4))) float f32x4;    // MFMA C/D frag

__device__ __forceinline__ float bf2f(unsigned short u) {
    return __uint_as_float(((unsigned)u) << 16);
}
__device__ __forceinline__ unsigned short f2bf(float f) {
    unsigned x = __float_as_uint(f);
    return (unsigned short)((x + 0x7FFFu + ((x >> 16) & 1u)) >> 16);  // RNE
}
// legacy math for fallback kernel (natural units)
__device__ __forceinline__ float sigm(float x) {
    const float e = __expf(-x);
    return __builtin_amdgcn_rcpf(1.f + e);
}
__device__ __forceinline__ float tanh_f(float x) {
    const float e = __expf(-2.f * x);
    return (1.f - e) * __builtin_amdgcn_rcpf(1.f + e);
}
__device__ __forceinline__ float rdlf(float v, int k) {
    return __int_as_float(__builtin_amdgcn_readlane(__float_as_int(v), k));
}
// DPP lane exchange (pure VALU; no LDS pipe)
template <int CTRL>
__device__ __forceinline__ unsigned dppq_u(unsigned v) {
    return (unsigned)__builtin_amdgcn_update_dpp(0, (int)v, CTRL, 0xF, 0xF, true);
}
template <int CTRL>
__device__ __forceinline__ float dppq_f(float v) {
    return __uint_as_float(dppq_u<CTRL>(__float_as_uint(v)));
}
#define DPP_XOR2   0x4E    // quad_perm [2,3,0,1] : partner unit (lane^2)
#define DPP_BODD   0xF5    // quad_perm [1,1,3,3] : broadcast odd lane of pair
#define DPP_BEVN   0xA0    // quad_perm [0,0,2,2] : broadcast even lane of pair
#define DPP_HMIRR  0x141   // row_half_mirror: lane l -> l^7  (quad p -> p^1)
#define DPP_ROR8   0x128   // row rotate 8:    lane l -> l^8  (quad p -> p^2)
#define DPP_MIRR   0x140   // row_mirror:      lane l -> l^15 (quad p -> p^3)

// dup-pair gate-column mapping: lane l -> first col ca, second col ca+64
__device__ __host__ __forceinline__ int col_a(int l) {
    return (l >> 1) + 32 * (l & 1);
}

// ---------------------------------------------------------------------------
// Inline dtype detector (true -> fp32 buffers, false -> bf16 buffers).
// Wave-parallel; every block computes it redundantly (1 load + ballot).
// ---------------------------------------------------------------------------
__device__ __forceinline__ bool detect_f32(const unsigned* __restrict__ bias_w,
                                           int lane) {
    const unsigned u  = bias_w[lane];
    const unsigned lo = u & 0xFFFFu;
    const float vlo = __uint_as_float(lo << 16);
    const float vhi = __uint_as_float(u & 0xFFFF0000u);
    const bool nz_even = (lo != 0u);
    const bool big = !(fabsf(vlo) < 1e6f) || !(fabsf(vhi) < 1e6f);
    const unsigned long long nz = __ballot(nz_even);
    const unsigned long long bg = __ballot(big);
    return (nz == 0ull || bg != 0ull);
}

// ---------------------------------------------------------------------------
// Token z-table, dup-pair permuted, prescaled by log2(e), g-columns by 2x,
// and i-columns (even-lane a-entries) biased by +1 so the scan's rcp gives
// 2*sigma directly:
//   ZK[v][2l]   = log2e * z_x[col_a(l)] + (l even ? 1 : 0)
//   ZK[v][2l+1] = log2e * s * z_x[col_a(l)+64], s=2 for even l (g), 1 (o)
// 8 vocab rows per block: weight regs loaded once, reused 8x.
// ---------------------------------------------------------------------------
#define ZK_RPB 8
__global__ __launch_bounds__(64) void zk_kernel(
    const void* __restrict__ emb, const void* __restrict__ Wk,
    const void* __restrict__ bias, float* __restrict__ ZK)
{
    const int l  = threadIdx.x;
    const int v0 = blockIdx.x * ZK_RPB;
    const bool f32 = detect_f32((const unsigned*)bias, l);
    const int ca = col_a(l), cb = ca + 64;
    const float ba_add = ((l & 1) == 0) ? 1.f : 0.f;     // i-col exp-fold bias
    const float sb = ((l & 1) == 0) ? 2.f * LOG2E : LOG2E;

    float wa[EMB], wb[EMB], ba, bb;
    if (f32) {
        const float* W = (const float*)Wk;
        const float* B = (const float*)bias;
#pragma unroll
        for (int e = 0; e < EMB; ++e) { wa[e] = W[e * G + ca]; wb[e] = W[e * G + cb]; }
        ba = B[ca]; bb = B[cb];
    } else {
        const unsigned short* W = (const unsigned short*)Wk;
        const unsigned short* B = (const unsigned short*)bias;
#pragma unroll
        for (int e = 0; e < EMB; ++e) { wa[e] = bf2f(W[e * G + ca]); wb[e] = bf2f(W[e * G + cb]); }
        ba = bf2f(B[ca]); bb = bf2f(B[cb]);
    }

#pragma unroll
    for (int r = 0; r < ZK_RPB; ++r) {
        const int v = v0 + r;
        float x[EMB];
        if (f32) {
            const float* E = (const float*)emb + (size_t)v * EMB;
#pragma unroll
            for (int e = 0; e < EMB; ++e) x[e] = E[e];
        } else {
            const unsigned short* E = (const unsigned short*)emb + (size_t)v * EMB;
#pragma unroll
            for (int e = 0; e < EMB; ++e) x[e] = bf2f(E[e]);
        }
        float za = ba, zb = bb;
#pragma unroll
        for (int e = 0; e < EMB; ++e) {
            za = fmaf(x[e], wa[e], za);
            zb = fmaf(x[e], wb[e], zb);
        }
        v2f o2;
        o2.x = fmaf(za, LOG2E, ba_add);
        o2.y = zb * sb;
        *(v2f*)(ZK + (size_t)v * G + 2 * l) = o2;
    }
}

// ---------------------------------------------------------------------------
// Scan (dup-pair + MFMA): lane l owns hidden unit j=l>>1, half=l&1.
// h->h chain per step (depth-3 A-pack): add(round) -> xor2 -> {3 dpp rh ||
// 3 dpp prt} -> 4 perm -> 8 MFMA (C=0, z-wait hidden behind them) ->
// 2 cndmask sel -> add z -> exp2 -> add -> rcp (one rcp = 2i even | f odd)
// -> q mul -> dpp-add cN (cS = -2log2e*c domain) -> exp2 -> add -> rcp ->
// fma hN -> mask.  ZERO DS instructions in the recurrence chain.
// ---------------------------------------------------------------------------
template <bool F32OUT>
__device__ __forceinline__ void scan_zk_loop(
    const int* __restrict__ trow, const float* __restrict__ ZK,
    void* __restrict__ orow, const short8 (&Bf)[8], int lane)
{
    const bool  h0  = (lane & 1) == 0;          // half 0: (i,g); half 1: (f,o)
    const float Kc  = h0 ? 0.5f : 1.0f;         // rcp add-const for a-side
    const int   oj  = lane >> 1;                // my hidden unit
    const int   g4  = (lane >> 4) & 3;          // which MFMA holds my column
    const bool  u_odd = (lane >> 1) & 1;        // my unit index parity
    const unsigned psel   = u_odd ? 0x03020706u : 0x07060302u;  // own selector
    const unsigned psel_o = u_odd ? 0x07060302u : 0x03020706u;  // mirrored-lane
    const int   lm  = lane & 15;

    const f32x4 zc = {0.f, 0.f, 0.f, 0.f};
    float h = 0.f, cS = 0.f;                    // cS = -2log2e * c

    // ---- tokens as scalars: one coalesced vector load per 16-chunk,
    //      extracted to SGPRs via readlane ----
    int tva = trow[lm];           // chunk 0
    int tvb = trow[16 + lm];      // chunk 1
    int tc[16], tn[16];
#pragma unroll
    for (int p = 0; p < 16; ++p) tc[p] = __builtin_amdgcn_readlane(tva, p);
#pragma unroll
    for (int p = 0; p < 16; ++p) tn[p] = __builtin_amdgcn_readlane(tvb, p);

    // ---- ZK prefetch ring, distance 8 ----
    v2f pz[8];
#pragma unroll
    for (int d = 0; d < 8; ++d)
        pz[d] = *(const v2f*)(ZK + (size_t)tc[d] * G + 2 * lane);

    for (int cc = 0; cc < TT / 16; ++cc) {
        const int base = cc * 16;
        // issue chunk cc+2 token vector load early (clamped at tail)
        const int nxtc = (cc + 2 < TT / 16) ? (cc + 2) : (TT / 16 - 1);
        const int tvc = trow[nxtc * 16 + lm];
#pragma unroll
        for (int u = 0; u < 16; ++u) {
            const int t = base + u;
            const v2f z = pz[u & 7];
            {   // prefetch z for t+8 (scalar token -> saddr-form load)
                const int ptok = (u + 8 < 16) ? tc[u + 8] : tn[u - 8];
                pz[u & 7] = *(const v2f*)(ZK + (size_t)ptok * G + 2 * lane);
            }

            // ---- A-frag pack, depth 3: round; partner via xor2; three
            //      row-scoped mirrors of BOTH rh and prt in parallel; then
            //      4 perms. hmirr (l^7) and mirror (l^15) flip the lane's
            //      unit-parity bit -> use psel_o there; ror8 (l^8) keeps it.
            //      Slot q holds pair(p^q); compensated in B-frag k-perm. ----
            const unsigned rh  = __float_as_uint(h) + 0x8000u;   // round-half-up
            const unsigned prt = dppq_u<DPP_XOR2>(rh);           // partner unit
            const unsigned rh1 = dppq_u<DPP_HMIRR>(rh);
            const unsigned rh2 = dppq_u<DPP_ROR8 >(rh);
            const unsigned rh3 = dppq_u<DPP_MIRR >(rh);
            const unsigned pt1 = dppq_u<DPP_HMIRR>(prt);
            const unsigned pt2 = dppq_u<DPP_ROR8 >(prt);
            const unsigned pt3 = dppq_u<DPP_MIRR >(prt);
            union { unsigned u4[4]; short8 s8; } au;
            au.u4[0] = __builtin_amdgcn_perm(prt, rh,  psel);
            au.u4[1] = __builtin_amdgcn_perm(pt1, rh1, psel_o);
            au.u4[2] = __builtin_amdgcn_perm(pt2, rh2, psel);
            au.u4[3] = __builtin_amdgcn_perm(pt3, rh3, psel_o);
            const short8 Af = au.s8;

            // ---- 8 MFMAs, C = 0 (z added after; its load hides here) ----
            f32x4 d0 = __builtin_amdgcn_mfma_f32_16x16x32_bf16(Af, Bf[0], zc, 0, 0, 0);
            f32x4 d1 = __builtin_amdgcn_mfma_f32_16x16x32_bf16(Af, Bf[1], zc, 0, 0, 0);
            f32x4 d2 = __builtin_amdgcn_mfma_f32_16x16x32_bf16(Af, Bf[2], zc, 0, 0, 0);
            f32x4 d3 = __builtin_amdgcn_mfma_f32_16x16x32_bf16(Af, Bf[3], zc, 0, 0, 0);
            f32x4 d4 = __builtin_amdgcn_mfma_f32_16x16x32_bf16(Af, Bf[4], zc, 0, 0, 0);
            f32x4 d5 = __builtin_amdgcn_mfma_f32_16x16x32_bf16(Af, Bf[5], zc, 0, 0, 0);
            f32x4 d6 = __builtin_amdgcn_mfma_f32_16x16x32_bf16(Af, Bf[6], zc, 0, 0, 0);
            f32x4 d7 = __builtin_amdgcn_mfma_f32_16x16x32_bf16(Af, Bf[7], zc, 0, 0, 0);

            // my columns: a-side from d[g4], b-side from d[4+g4]
            const float mva = (g4 < 2) ? (g4 == 0 ? d0.x : d1.x)
                                       : (g4 == 2 ? d2.x : d3.x);
            const float mvb = (g4 < 2) ? (g4 == 0 ? d4.x : d5.x)
                                       : (g4 == 2 ? d6.x : d7.x);
            const float za = z.x + mva;   // even: log2e*z_i + 1 | odd: log2e*z_f
            const float zb = z.y + mvb;   // even: 2log2e*z_g    | odd: log2e*z_o

            // one rcp gives 2i (even, Kc=0.5) or f (odd, Kc=1)
            const float exa = __builtin_amdgcn_exp2f(-za);
            const float exb = __builtin_amdgcn_exp2f(-zb);
            const float r1  = __builtin_amdgcn_rcpf(exa + Kc);
            const float s2  = __builtin_amdgcn_rcpf(exb + 1.f);  // sig(2zg)|o
            // cS-domain i*g: s2p = -2log2e*(s2-0.5) = -log2e*g (even lanes)
            const float s2p = fmaf(s2, -TWOLOG2E, LOG2E);
            const float q   = r1 * s2p;                 // even: -2log2e*(i*g)
            const float fc  = dppq_f<DPP_BODD>(r1) * cS;
            const float cN  = dppq_f<DPP_BEVN>(q) + fc; // -2log2e*c_new
            const float oG  = dppq_f<DPP_BODD>(s2);     // o

            // h = o*tanh(c) = 2o*rcp(1+e^{-2c}) - o ; e^{-2c} = exp2(cS)
            const float exh = __builtin_amdgcn_exp2f(cN);
            const float rr  = __builtin_amdgcn_rcpf(exh + 1.f);
            const float oo  = oG + oG;                  // off-chain
            const float hN  = fmaf(oo, rr, -oG);

            const bool m = tc[u] != 0;                  // scalar token
            cS = m ? cN : cS;
            h  = m ? hN : h;

            const int oi = t * HID + oj;     // pair lanes: same addr+data
            if (F32OUT) __builtin_nontemporal_store(h, (float*)orow + oi);
            else        __builtin_nontemporal_store(f2bf(h), (unsigned short*)orow + oi);
        }
        // rotate token chunks (SALU), extract prefetched chunk cc+2
#pragma unroll
        for (int p = 0; p < 16; ++p) tc[p] = tn[p];
#pragma unroll
        for (int p = 0; p < 16; ++p) tn[p] = __builtin_amdgcn_readlane(tvc, p);
    }
}

__global__ __launch_bounds__(64) void scan_zk_kernel(
    const int* __restrict__ tokens, const float* __restrict__ ZK,
    const void* __restrict__ Wr, const void* __restrict__ bias,
    void* __restrict__ out)
{
    const int lane = threadIdx.x, b = blockIdx.x;
    const bool f32 = detect_f32((const unsigned*)bias, lane);

    // B-frags: MFMA q<4 -> first-gate cols ca(16q+n); q>=4 -> cb(16(q-4)+n).
    // Lane holds B[k=(lane>>4)*8+j][n=lane&15], k XOR-permuted per MFMA
    // (j ^ (q<<1)) to absorb the DPP all-gather's pair(p^q) layout; scaled by
    // log2e, and additionally by 2 for g-columns (p>=4, even n).
    short8 Bf[8];
    const int n  = lane & 15;
    const int k0 = (lane >> 4) * 8;
#pragma unroll
    for (int p = 0; p < 8; ++p) {
        const int ell = 16 * (p & 3) + n;
        const int col = (p < 4) ? col_a(ell) : (col_a(ell) + 64);
        const int jx  = (p & 3) << 1;         // k-pair XOR permutation
        const float sc = (p >= 4 && (n & 1) == 0) ? 2.f * LOG2E : LOG2E;
        short el[8];
        if (f32) {
            const float* W = (const float*)Wr;
#pragma unroll
            for (int j = 0; j < 8; ++j)
                el[j] = (short)f2bf(W[(k0 + (j ^ jx)) * G + col] * sc);
        } else {
            const unsigned short* W = (const unsigned short*)Wr;
#pragma unroll
            for (int j = 0; j < 8; ++j)
                el[j] = (short)f2bf(bf2f(W[(k0 + (j ^ jx)) * G + col]) * sc);
        }
        short8 s;
#pragma unroll
        for (int j = 0; j < 8; ++j) s[j] = el[j];
        Bf[p] = s;
    }

    const int* trow = tokens + (size_t)b * TT;
    if (f32) scan_zk_loop<true >(trow, ZK, (char*)out + (size_t)b * TT * HID * 4, Bf, lane);
    else     scan_zk_loop<false>(trow, ZK, (char*)out + (size_t)b * TT * HID * 2, Bf, lane);
}

// ---------------------------------------------------------------------------
// Fallback (workspace too small): proven R2/R3 fused kernel (natural units).
// ---------------------------------------------------------------------------
template <bool F32>
__device__ __forceinline__ void row_load(const void* emb, int tok, uint4* r) {
    if (F32) { const uint4* p = (const uint4*)((const float*)emb + (size_t)tok*EMB);
               r[0]=p[0]; r[1]=p[1]; r[2]=p[2]; r[3]=p[3]; }
    else     { const uint4* p = (const uint4*)((const unsigned short*)emb + (size_t)tok*EMB);
               r[0]=p[0]; r[1]=p[1]; }
}
template <bool F32>
__device__ __forceinline__ void row_unpack(const uint4* r, float* x) {
    if (F32) {
        const unsigned w[16] = {r[0].x,r[0].y,r[0].z,r[0].w, r[1].x,r[1].y,r[1].z,r[1].w,
                                r[2].x,r[2].y,r[2].z,r[2].w, r[3].x,r[3].y,r[3].z,r[3].w};
#pragma unroll
        for (int e = 0; e < 16; ++e) x[e] = __uint_as_float(w[e]);
    } else {
        const unsigned w[8] = {r[0].x,r[0].y,r[0].z,r[0].w, r[1].x,r[1].y,r[1].z,r[1].w};
#pragma unroll
        for (int q = 0; q < 8; ++q) {
            x[2*q]   = __uint_as_float(w[q] << 16);
            x[2*q+1] = __uint_as_float(w[q] & 0xFFFF0000u);
        }
    }
}

template <bool F32>
__device__ __forceinline__ void scan_fused_loop(
    const int* __restrict__ trow, const void* __restrict__ emb, void* orow,
    const float (&wka)[EMB], const float (&wkb)[EMB],
    const float (&wra)[HID], const float (&wrb)[HID],
    float za0, float zb0, const int* tl, int lane)
{
    const bool  lo  = lane < HID;
    const float zsc = lo ? 2.f : 1.f, gm = lo ? 2.f : 1.f, ga = lo ? -1.f : 0.f;
    float h = 0.f, c = 0.f;
    uint4 praw[2][4];
    row_load<F32>(emb, trow[0], praw[0]);
    row_load<F32>(emb, trow[1], praw[1]);

    for (int tt = 0; tt < TT; tt += 2) {
#pragma unroll
        for (int u = 0; u < 2; ++u) {
            const int t = tt + u;
            float x[EMB];
            row_unpack<F32>(praw[u], x);
            int tn = t + 2; tn = tn > TT - 1 ? TT - 1 : tn;
            row_load<F32>(emb, tl[tn], praw[u]);
            float za = za0, zb = zb0;
#pragma unroll
            for (int e = 0; e < EMB; ++e) { za = fmaf(x[e], wka[e], za); zb = fmaf(x[e], wkb[e], zb); }
#pragma unroll
            for (int k = 0; k < HID; ++k) {
                const float hk = rdlf(h, k);
                za = fmaf(hk, wra[k], za);
                zb = fmaf(hk, wrb[k], zb);
            }
            const float a1 = sigm(za);
            const float s2 = sigm(zb * zsc);
            const float a2 = fmaf(s2, gm, ga);
            const float x1 = __shfl_xor(a1, 32);
            const float x2 = __shfl_xor(a2, 32);
            const float iV = lo ? a1 : x1, fV = lo ? x1 : a1;
            const float gV = lo ? a2 : x2, oV = lo ? x2 : a2;
            const float cN = fmaf(fV, c, iV * gV);
            const float hN = oV * tanh_f(cN);
            const bool  m  = tl[t] != 0;
            c = m ? cN : c;
            h = m ? hN : h;
            const int oi = t * HID + (lane & (HID - 1));
            if (F32) ((float*)orow)[oi] = h;
            else     ((unsigned short*)orow)[oi] = f2bf(h);
        }
    }
}

__global__ __launch_bounds__(64) void scan_fused_kernel(
    const int* __restrict__ tokens, const void* __restrict__ emb,
    const void* __restrict__ Wk, const void* __restrict__ Wr,
    const void* __restrict__ bias, void* __restrict__ out)
{
    __shared__ int tl[TT];
    const int lane = threadIdx.x, b = blockIdx.x;
    const bool f32 = detect_f32((const unsigned*)bias, lane);
    const int* trow = tokens + (size_t)b * TT;
    for (int t = lane; t < TT; t += 64) tl[t] = trow[t];

    float wka[EMB], wkb[EMB], wra[HID], wrb[HID], za0, zb0;
    if (f32) {
        const float* WK = (const float*)Wk; const float* WR = (const float*)Wr;
        const float* B  = (const float*)bias;
#pragma unroll
        for (int e = 0; e < EMB; ++e) { wka[e] = WK[e*G + lane]; wkb[e] = WK[e*G + lane + 64]; }
#pragma unroll
        for (int k = 0; k < HID; ++k) { wra[k] = WR[k*G + lane]; wrb[k] = WR[k*G + lane + 64]; }
        za0 = B[lane]; zb0 = B[lane + 64];
    } else {
        const unsigned short* WK = (const unsigned short*)Wk;
        const unsigned short* WR = (const unsigned short*)Wr;
        const unsigned short* B  = (const unsigned short*)bias;
#pragma unroll
        for (int e = 0; e < EMB; ++e) { wka[e] = bf2f(WK[e*G + lane]); wkb[e] = bf2f(WK[e*G + lane + 64]); }
#pragma unroll
        for (int k = 0; k < HID; ++k) { wra[k] = bf2f(WR[k*G + lane]); wrb[k] = bf2f(WR[k*G + lane + 64]); }
        za0 = bf2f(B[lane]); zb0 = bf2f(B[lane + 64]);
    }
    __syncthreads();

    if (f32) scan_fused_loop<true >(trow, emb, (char*)out + (size_t)b*TT*HID*4,
                                    wka, wkb, wra, wrb, za0, zb0, tl, lane);
    else     scan_fused_loop<false>(trow, emb, (char*)out + (size_t)b*TT*HID*2,
                                    wka, wkb, wra, wrb, za0, zb0, tl, lane);
}

// ---------------------------------------------------------------------------
extern "C" void kernel_launch(void* const* d_in, const int* in_sizes, int n_in,
                              void* d_out, int out_size, void* d_ws, size_t ws_size,
                              hipStream_t stream) {
    const int*  tokens = (const int*)d_in[0];
    const void* emb    = d_in[1];
    const void* Wk     = d_in[2];
    const void* Wr     = d_in[3];
    const void* bias   = d_in[4];

    const size_t zk_off   = 256;
    const size_t zk_bytes = (size_t)VOC * G * sizeof(float);   // 2.56 MB

    if (ws_size >= zk_off + zk_bytes) {
        float* ZK = (float*)((char*)d_ws + zk_off);
        zk_kernel<<<VOC / ZK_RPB, 64, 0, stream>>>(emb, Wk, bias, ZK);
        scan_zk_kernel<<<BB, 64, 0, stream>>>(tokens, ZK, Wr, bias, d_out);
    } else {
        scan_fused_kernel<<<BB, 64, 0, stream>>>(tokens, emb, Wk, Wr, bias, d_out);
    }
}

// Round 5
// 438.015 us; speedup vs baseline: 1.1246x; 1.0242x over previous
//
#include <hip/hip_runtime.h>

#define G    128          // 4*HID
#define HID  32
#define EMB  16
#define BB   256
#define TT   2048
#define VOC  5000

#define LOG2E      1.44269504088896340736f
#define TWOLOG2E   2.88539008177792681472f

typedef float v2f __attribute__((ext_vector_type(2)));
typedef __attribute__((ext_vector_type(8))) short short8;   // 8 bf16 (4 VGPRs)
typedef __attribute__((ext_vector_type(4))) float f32x4;    // MFMA C/D frag

__device__ __forceinline__ float bf2f(unsigned short u) {
    return __uint_as_float(((unsigned)u) << 16);
}
__device__ __forceinline__ unsigned short f2bf(float f) {
    unsigned x = __float_as_uint(f);
    return (unsigned short)((x + 0x7FFFu + ((x >> 16) & 1u)) >> 16);  // RNE
}
// legacy math for fallback kernel (natural units)
__device__ __forceinline__ float sigm(float x) {
    const float e = __expf(-x);
    return __builtin_amdgcn_rcpf(1.f + e);
}
__device__ __forceinline__ float tanh_f(float x) {
    const float e = __expf(-2.f * x);
    return (1.f - e) * __builtin_amdgcn_rcpf(1.f + e);
}
__device__ __forceinline__ float rdlf(float v, int k) {
    return __int_as_float(__builtin_amdgcn_readlane(__float_as_int(v), k));
}
// DPP lane exchange (pure VALU; no LDS pipe)
template <int CTRL>
__device__ __forceinline__ unsigned dppq_u(unsigned v) {
    return (unsigned)__builtin_amdgcn_update_dpp(0, (int)v, CTRL, 0xF, 0xF, true);
}
template <int CTRL>
__device__ __forceinline__ float dppq_f(float v) {
    return __uint_as_float(dppq_u<CTRL>(__float_as_uint(v)));
}
#define DPP_XOR2   0x4E    // quad_perm [2,3,0,1] : partner unit (lane^2)
#define DPP_BODD   0xF5    // quad_perm [1,1,3,3] : broadcast odd lane of pair
#define DPP_BEVN   0xA0    // quad_perm [0,0,2,2] : broadcast even lane of pair
#define DPP_HMIRR  0x141   // row_half_mirror: lane l -> l^7  (quad p -> p^1)
#define DPP_ROR8   0x128   // row rotate 8:    lane l -> l^8  (quad p -> p^2)
#define DPP_MIRR   0x140   // row_mirror:      lane l -> l^15 (quad p -> p^3)

// dup-pair gate-column mapping: lane l -> first col ca, second col ca+64
__device__ __host__ __forceinline__ int col_a(int l) {
    return (l >> 1) + 32 * (l & 1);
}

// ---------------------------------------------------------------------------
// Inline dtype detector (true -> fp32 buffers, false -> bf16 buffers).
// Wave-parallel; every block computes it redundantly (1 load + ballot).
// ---------------------------------------------------------------------------
__device__ __forceinline__ bool detect_f32(const unsigned* __restrict__ bias_w,
                                           int lane) {
    const unsigned u  = bias_w[lane];
    const unsigned lo = u & 0xFFFFu;
    const float vlo = __uint_as_float(lo << 16);
    const float vhi = __uint_as_float(u & 0xFFFF0000u);
    const bool nz_even = (lo != 0u);
    const bool big = !(fabsf(vlo) < 1e6f) || !(fabsf(vhi) < 1e6f);
    const unsigned long long nz = __ballot(nz_even);
    const unsigned long long bg = __ballot(big);
    return (nz == 0ull || bg != 0ull);
}

// ---------------------------------------------------------------------------
// Token z-table, dup-pair permuted, prescaled by log2(e), g-columns by 2x,
// and i-columns (even-lane a-entries) biased by +1 so the scan's rcp gives
// 2*sigma directly:
//   ZK[v][2l]   = log2e * z_x[col_a(l)] + (l even ? 1 : 0)
//   ZK[v][2l+1] = log2e * s * z_x[col_a(l)+64], s=2 for even l (g), 1 (o)
// 8 vocab rows per block: weight regs loaded once, reused 8x.
// ---------------------------------------------------------------------------
#define ZK_RPB 8
__global__ __launch_bounds__(64) void zk_kernel(
    const void* __restrict__ emb, const void* __restrict__ Wk,
    const void* __restrict__ bias, float* __restrict__ ZK)
{
    const int l  = threadIdx.x;
    const int v0 = blockIdx.x * ZK_RPB;
    const bool f32 = detect_f32((const unsigned*)bias, l);
    const int ca = col_a(l), cb = ca + 64;
    const float ba_add = ((l & 1) == 0) ? 1.f : 0.f;     // i-col exp-fold bias
    const float sb = ((l & 1) == 0) ? 2.f * LOG2E : LOG2E;

    float wa[EMB], wb[EMB], ba, bb;
    if (f32) {
        const float* W = (const float*)Wk;
        const float* B = (const float*)bias;
#pragma unroll
        for (int e = 0; e < EMB; ++e) { wa[e] = W[e * G + ca]; wb[e] = W[e * G + cb]; }
        ba = B[ca]; bb = B[cb];
    } else {
        const unsigned short* W = (const unsigned short*)Wk;
        const unsigned short* B = (const unsigned short*)bias;
#pragma unroll
        for (int e = 0; e < EMB; ++e) { wa[e] = bf2f(W[e * G + ca]); wb[e] = bf2f(W[e * G + cb]); }
        ba = bf2f(B[ca]); bb = bf2f(B[cb]);
    }

#pragma unroll
    for (int r = 0; r < ZK_RPB; ++r) {
        const int v = v0 + r;
        float x[EMB];
        if (f32) {
            const float* E = (const float*)emb + (size_t)v * EMB;
#pragma unroll
            for (int e = 0; e < EMB; ++e) x[e] = E[e];
        } else {
            const unsigned short* E = (const unsigned short*)emb + (size_t)v * EMB;
#pragma unroll
            for (int e = 0; e < EMB; ++e) x[e] = bf2f(E[e]);
        }
        float za = ba, zb = bb;
#pragma unroll
        for (int e = 0; e < EMB; ++e) {
            za = fmaf(x[e], wa[e], za);
            zb = fmaf(x[e], wb[e], zb);
        }
        v2f o2;
        o2.x = fmaf(za, LOG2E, ba_add);
        o2.y = zb * sb;
        *(v2f*)(ZK + (size_t)v * G + 2 * l) = o2;
    }
}

// ---------------------------------------------------------------------------
// Scan (dup-pair + MFMA): lane l owns hidden unit j=l>>1, half=l&1.
// h->h chain per step: pack (add, dpp, perm, dpp; R2-proven 5-op form) ->
// 8 MFMA with b-side (deep path) ISSUED FIRST -> sel -> add z -> exp2 ->
// add -> rcp (one rcp = 2i even | f odd) -> q fma (rA/rB pre-scaled on the
// shallow a-path) -> dpp-add cN (cS = -2log2e*c domain) -> exp2 -> add ->
// rcp -> fma hN.  token==0 handled by a wave-uniform rare branch (SALU),
// not cndmask.  ZERO DS instructions in the recurrence chain.
// ---------------------------------------------------------------------------
template <bool F32OUT>
__device__ __forceinline__ void scan_zk_loop(
    const int* __restrict__ trow, const float* __restrict__ ZK,
    void* __restrict__ orow, const short8 (&Bf)[8], int lane)
{
    const bool  h0  = (lane & 1) == 0;          // half 0: (i,g); half 1: (f,o)
    const float Kc  = h0 ? 0.5f : 1.0f;         // rcp add-const for a-side
    const int   oj  = lane >> 1;                // my hidden unit
    const int   g4  = (lane >> 4) & 3;          // which MFMA holds my column
    const bool  u_odd = (lane >> 1) & 1;        // my unit index parity
    const unsigned psel = u_odd ? 0x03020706u : 0x07060302u;  // v_perm selector
    const int   lm  = lane & 15;

    const f32x4 zc = {0.f, 0.f, 0.f, 0.f};
    float h = 0.f, cS = 0.f;                    // cS = -2log2e * c

    // ---- tokens as scalars: one coalesced vector load per 16-chunk,
    //      extracted to SGPRs via readlane ----
    int tva = trow[lm];           // chunk 0
    int tvb = trow[16 + lm];      // chunk 1
    int tc[16], tn[16];
#pragma unroll
    for (int p = 0; p < 16; ++p) tc[p] = __builtin_amdgcn_readlane(tva, p);
#pragma unroll
    for (int p = 0; p < 16; ++p) tn[p] = __builtin_amdgcn_readlane(tvb, p);

    // ---- ZK prefetch ring, distance 8 ----
    v2f pz[8];
#pragma unroll
    for (int d = 0; d < 8; ++d)
        pz[d] = *(const v2f*)(ZK + (size_t)tc[d] * G + 2 * lane);

    for (int cc = 0; cc < TT / 16; ++cc) {
        const int base = cc * 16;
        // issue chunk cc+2 token vector load early (clamped at tail)
        const int nxtc = (cc + 2 < TT / 16) ? (cc + 2) : (TT / 16 - 1);
        const int tvc = trow[nxtc * 16 + lm];
#pragma unroll
        for (int u = 0; u < 16; ++u) {
            const int t = base + u;
            const v2f z = pz[u & 7];
            {   // prefetch z for t+8 (scalar token -> saddr-form load)
                const int ptok = (u + 8 < 16) ? tc[u + 8] : tn[u - 8];
                pz[u & 7] = *(const v2f*)(ZK + (size_t)ptok * G + 2 * lane);
            }

            // ---- A-frag pack (R2-proven 5-op form): round, partner via
            //      DPP xor2, variable-sel v_perm, 3 static DPP gathers.
            //      Slot q holds pair(p^q); compensated in B-frag k-perm. ----
            const unsigned rh  = __float_as_uint(h) + 0x8000u;   // round-half-up
            const unsigned prt = dppq_u<DPP_XOR2>(rh);           // partner unit
            const unsigned pair = __builtin_amdgcn_perm(prt, rh, psel);
            const unsigned q1 = dppq_u<DPP_HMIRR>(pair);         // pair(p^1)
            const unsigned q2 = dppq_u<DPP_ROR8 >(pair);         // pair(p^2)
            const unsigned q3 = dppq_u<DPP_MIRR >(pair);         // pair(p^3)
            union { unsigned u4[4]; short8 s8; } au;
            au.u4[0] = pair; au.u4[1] = q1; au.u4[2] = q2; au.u4[3] = q3;
            const short8 Af = au.s8;

            // ---- 8 MFMAs, C = 0.  b-side (deep gate path) issued FIRST so
            //      the s2->q->cN chain gets its data ~20 cyc earlier. ----
            f32x4 d4 = __builtin_amdgcn_mfma_f32_16x16x32_bf16(Af, Bf[4], zc, 0, 0, 0);
            f32x4 d5 = __builtin_amdgcn_mfma_f32_16x16x32_bf16(Af, Bf[5], zc, 0, 0, 0);
            f32x4 d6 = __builtin_amdgcn_mfma_f32_16x16x32_bf16(Af, Bf[6], zc, 0, 0, 0);
            f32x4 d7 = __builtin_amdgcn_mfma_f32_16x16x32_bf16(Af, Bf[7], zc, 0, 0, 0);
            f32x4 d0 = __builtin_amdgcn_mfma_f32_16x16x32_bf16(Af, Bf[0], zc, 0, 0, 0);
            f32x4 d1 = __builtin_amdgcn_mfma_f32_16x16x32_bf16(Af, Bf[1], zc, 0, 0, 0);
            f32x4 d2 = __builtin_amdgcn_mfma_f32_16x16x32_bf16(Af, Bf[2], zc, 0, 0, 0);
            f32x4 d3 = __builtin_amdgcn_mfma_f32_16x16x32_bf16(Af, Bf[3], zc, 0, 0, 0);

            // my columns: b-side first (deep path), a-side second
            const float mvb = (g4 < 2) ? (g4 == 0 ? d4.x : d5.x)
                                       : (g4 == 2 ? d6.x : d7.x);
            const float mva = (g4 < 2) ? (g4 == 0 ? d0.x : d1.x)
                                       : (g4 == 2 ? d2.x : d3.x);
            const float zb = z.y + mvb;   // even: 2log2e*z_g    | odd: log2e*z_o
            const float za = z.x + mva;   // even: log2e*z_i + 1 | odd: log2e*z_f

            // one rcp gives 2i (even, Kc=0.5) or f (odd, Kc=1)
            const float exb = __builtin_amdgcn_exp2f(-zb);
            const float exa = __builtin_amdgcn_exp2f(-za);
            const float s2  = __builtin_amdgcn_rcpf(exb + 1.f);  // sig(2zg)|o
            const float r1  = __builtin_amdgcn_rcpf(exa + Kc);
            // a-path pre-scales so the deep b-path does ONE fma to q:
            // q = r1*(-2L*s2 + L) = fma(s2, -2L*r1, L*r1)
            const float rA  = r1 * -TWOLOG2E;
            const float rB  = r1 * LOG2E;
            const float q   = fmaf(s2, rA, rB);         // even: -2log2e*(i*g)
            const float fc  = dppq_f<DPP_BODD>(r1) * cS;
            float cN  = dppq_f<DPP_BEVN>(q) + fc;       // -2log2e*c_new
            const float oG  = dppq_f<DPP_BODD>(s2);     // o

            // h = o*tanh(c) = 2o*rcp(1+e^{-2c}) - o ; e^{-2c} = exp2(cS)
            const float exh = __builtin_amdgcn_exp2f(cN);
            const float rr  = __builtin_amdgcn_rcpf(exh + 1.f);
            const float oo  = oG + oG;                  // off-chain
            float hN  = fmaf(oo, rr, -oG);

            // token==0 is ~0.02%: wave-uniform SALU branch, no on-chain sel
            if (__builtin_expect(tc[u] == 0, 0)) { cN = cS; hN = h; }
            cS = cN; h = hN;

            const int oi = t * HID + oj;     // pair lanes: same addr+data
            if (F32OUT) __builtin_nontemporal_store(h, (float*)orow + oi);
            else        __builtin_nontemporal_store(f2bf(h), (unsigned short*)orow + oi);
        }
        // rotate token chunks (SALU), extract prefetched chunk cc+2
#pragma unroll
        for (int p = 0; p < 16; ++p) tc[p] = tn[p];
#pragma unroll
        for (int p = 0; p < 16; ++p) tn[p] = __builtin_amdgcn_readlane(tvc, p);
    }
}

__global__ __launch_bounds__(64) void scan_zk_kernel(
    const int* __restrict__ tokens, const float* __restrict__ ZK,
    const void* __restrict__ Wr, const void* __restrict__ bias,
    void* __restrict__ out)
{
    const int lane = threadIdx.x, b = blockIdx.x;
    const bool f32 = detect_f32((const unsigned*)bias, lane);

    // B-frags: MFMA q<4 -> first-gate cols ca(16q+n); q>=4 -> cb(16(q-4)+n).
    // Lane holds B[k=(lane>>4)*8+j][n=lane&15], k XOR-permuted per MFMA
    // (j ^ (q<<1)) to absorb the DPP all-gather's pair(p^q) layout; scaled by
    // log2e, and additionally by 2 for g-columns (p>=4, even n).
    short8 Bf[8];
    const int n  = lane & 15;
    const int k0 = (lane >> 4) * 8;
#pragma unroll
    for (int p = 0; p < 8; ++p) {
        const int ell = 16 * (p & 3) + n;
        const int col = (p < 4) ? col_a(ell) : (col_a(ell) + 64);
        const int jx  = (p & 3) << 1;         // k-pair XOR permutation
        const float sc = (p >= 4 && (n & 1) == 0) ? 2.f * LOG2E : LOG2E;
        short el[8];
        if (f32) {
            const float* W = (const float*)Wr;
#pragma unroll
            for (int j = 0; j < 8; ++j)
                el[j] = (short)f2bf(W[(k0 + (j ^ jx)) * G + col] * sc);
        } else {
            const unsigned short* W = (const unsigned short*)Wr;
#pragma unroll
            for (int j = 0; j < 8; ++j)
                el[j] = (short)f2bf(bf2f(W[(k0 + (j ^ jx)) * G + col]) * sc);
        }
        short8 s;
#pragma unroll
        for (int j = 0; j < 8; ++j) s[j] = el[j];
        Bf[p] = s;
    }

    const int* trow = tokens + (size_t)b * TT;
    if (f32) scan_zk_loop<true >(trow, ZK, (char*)out + (size_t)b * TT * HID * 4, Bf, lane);
    else     scan_zk_loop<false>(trow, ZK, (char*)out + (size_t)b * TT * HID * 2, Bf, lane);
}

// ---------------------------------------------------------------------------
// Fallback (workspace too small): proven R2/R3 fused kernel (natural units).
// ---------------------------------------------------------------------------
template <bool F32>
__device__ __forceinline__ void row_load(const void* emb, int tok, uint4* r) {
    if (F32) { const uint4* p = (const uint4*)((const float*)emb + (size_t)tok*EMB);
               r[0]=p[0]; r[1]=p[1]; r[2]=p[2]; r[3]=p[3]; }
    else     { const uint4* p = (const uint4*)((const unsigned short*)emb + (size_t)tok*EMB);
               r[0]=p[0]; r[1]=p[1]; }
}
template <bool F32>
__device__ __forceinline__ void row_unpack(const uint4* r, float* x) {
    if (F32) {
        const unsigned w[16] = {r[0].x,r[0].y,r[0].z,r[0].w, r[1].x,r[1].y,r[1].z,r[1].w,
                                r[2].x,r[2].y,r[2].z,r[2].w, r[3].x,r[3].y,r[3].z,r[3].w};
#pragma unroll
        for (int e = 0; e < 16; ++e) x[e] = __uint_as_float(w[e]);
    } else {
        const unsigned w[8] = {r[0].x,r[0].y,r[0].z,r[0].w, r[1].x,r[1].y,r[1].z,r[1].w};
#pragma unroll
        for (int q = 0; q < 8; ++q) {
            x[2*q]   = __uint_as_float(w[q] << 16);
            x[2*q+1] = __uint_as_float(w[q] & 0xFFFF0000u);
        }
    }
}

template <bool F32>
__device__ __forceinline__ void scan_fused_loop(
    const int* __restrict__ trow, const void* __restrict__ emb, void* orow,
    const float (&wka)[EMB], const float (&wkb)[EMB],
    const float (&wra)[HID], const float (&wrb)[HID],
    float za0, float zb0, const int* tl, int lane)
{
    const bool  lo  = lane < HID;
    const float zsc = lo ? 2.f : 1.f, gm = lo ? 2.f : 1.f, ga = lo ? -1.f : 0.f;
    float h = 0.f, c = 0.f;
    uint4 praw[2][4];
    row_load<F32>(emb, trow[0], praw[0]);
    row_load<F32>(emb, trow[1], praw[1]);

    for (int tt = 0; tt < TT; tt += 2) {
#pragma unroll
        for (int u = 0; u < 2; ++u) {
            const int t = tt + u;
            float x[EMB];
            row_unpack<F32>(praw[u], x);
            int tn = t + 2; tn = tn > TT - 1 ? TT - 1 : tn;
            row_load<F32>(emb, tl[tn], praw[u]);
            float za = za0, zb = zb0;
#pragma unroll
            for (int e = 0; e < EMB; ++e) { za = fmaf(x[e], wka[e], za); zb = fmaf(x[e], wkb[e], zb); }
#pragma unroll
            for (int k = 0; k < HID; ++k) {
                const float hk = rdlf(h, k);
                za = fmaf(hk, wra[k], za);
                zb = fmaf(hk, wrb[k], zb);
            }
            const float a1 = sigm(za);
            const float s2 = sigm(zb * zsc);
            const float a2 = fmaf(s2, gm, ga);
            const float x1 = __shfl_xor(a1, 32);
            const float x2 = __shfl_xor(a2, 32);
            const float iV = lo ? a1 : x1, fV = lo ? x1 : a1;
            const float gV = lo ? a2 : x2, oV = lo ? x2 : a2;
            const float cN = fmaf(fV, c, iV * gV);
            const float hN = oV * tanh_f(cN);
            const bool  m  = tl[t] != 0;
            c = m ? cN : c;
            h = m ? hN : h;
            const int oi = t * HID + (lane & (HID - 1));
            if (F32) ((float*)orow)[oi] = h;
            else     ((unsigned short*)orow)[oi] = f2bf(h);
        }
    }
}

__global__ __launch_bounds__(64) void scan_fused_kernel(
    const int* __restrict__ tokens, const void* __restrict__ emb,
    const void* __restrict__ Wk, const void* __restrict__ Wr,
    const void* __restrict__ bias, void* __restrict__ out)
{
    __shared__ int tl[TT];
    const int lane = threadIdx.x, b = blockIdx.x;
    const bool f32 = detect_f32((const unsigned*)bias, lane);
    const int* trow = tokens + (size_t)b * TT;
    for (int t = lane; t < TT; t += 64) tl[t] = trow[t];

    float wka[EMB], wkb[EMB], wra[HID], wrb[HID], za0, zb0;
    if (f32) {
        const float* WK = (const float*)Wk; const float* WR = (const float*)Wr;
        const float* B  = (const float*)bias;
#pragma unroll
        for (int e = 0; e < EMB; ++e) { wka[e] = WK[e*G + lane]; wkb[e] = WK[e*G + lane + 64]; }
#pragma unroll
        for (int k = 0; k < HID; ++k) { wra[k] = WR[k*G + lane]; wrb[k] = WR[k*G + lane + 64]; }
        za0 = B[lane]; zb0 = B[lane + 64];
    } else {
        const unsigned short* WK = (const unsigned short*)Wk;
        const unsigned short* WR = (const unsigned short*)Wr;
        const unsigned short* B  = (const unsigned short*)bias;
#pragma unroll
        for (int e = 0; e < EMB; ++e) { wka[e] = bf2f(WK[e*G + lane]); wkb[e] = bf2f(WK[e*G + lane + 64]); }
#pragma unroll
        for (int k = 0; k < HID; ++k) { wra[k] = bf2f(WR[k*G + lane]); wrb[k] = bf2f(WR[k*G + lane + 64]); }
        za0 = bf2f(B[lane]); zb0 = bf2f(B[lane + 64]);
    }
    __syncthreads();

    if (f32) scan_fused_loop<true >(trow, emb, (char*)out + (size_t)b*TT*HID*4,
                                    wka, wkb, wra, wrb, za0, zb0, tl, lane);
    else     scan_fused_loop<false>(trow, emb, (char*)out + (size_t)b*TT*HID*2,
                                    wka, wkb, wra, wrb, za0, zb0, tl, lane);
}

// ---------------------------------------------------------------------------
extern "C" void kernel_launch(void* const* d_in, const int* in_sizes, int n_in,
                              void* d_out, int out_size, void* d_ws, size_t ws_size,
                              hipStream_t stream) {
    const int*  tokens = (const int*)d_in[0];
    const void* emb    = d_in[1];
    const void* Wk     = d_in[2];
    const void* Wr     = d_in[3];
    const void* bias   = d_in[4];

    const size_t zk_off   = 256;
    const size_t zk_bytes = (size_t)VOC * G * sizeof(float);   // 2.56 MB

    if (ws_size >= zk_off + zk_bytes) {
        float* ZK = (float*)((char*)d_ws + zk_off);
        zk_kernel<<<VOC / ZK_RPB, 64, 0, stream>>>(emb, Wk, bias, ZK);
        scan_zk_kernel<<<BB, 64, 0, stream>>>(tokens, ZK, Wr, bias, d_out);
    } else {
        scan_fused_kernel<<<BB, 64, 0, stream>>>(tokens, emb, Wk, Wr, bias, d_out);
    }
}

// Round 6
// 430.933 us; speedup vs baseline: 1.1431x; 1.0164x over previous
//
#include <hip/hip_runtime.h>

#define G    128          // 4*HID
#define HID  32
#define EMB  16
#define BB   256
#define TT   2048
#define VOC  5000

#define LOG2E      1.44269504088896340736f
#define TWOLOG2E   2.88539008177792681472f

typedef float v2f __attribute__((ext_vector_type(2)));
typedef __attribute__((ext_vector_type(8))) short short8;   // 8 bf16 (4 VGPRs)
typedef __attribute__((ext_vector_type(4))) float f32x4;    // MFMA C/D frag

__device__ __forceinline__ float bf2f(unsigned short u) {
    return __uint_as_float(((unsigned)u) << 16);
}
__device__ __forceinline__ unsigned short f2bf(float f) {
    unsigned x = __float_as_uint(f);
    return (unsigned short)((x + 0x7FFFu + ((x >> 16) & 1u)) >> 16);  // RNE
}
// legacy math for fallback kernel (natural units)
__device__ __forceinline__ float sigm(float x) {
    const float e = __expf(-x);
    return __builtin_amdgcn_rcpf(1.f + e);
}
__device__ __forceinline__ float tanh_f(float x) {
    const float e = __expf(-2.f * x);
    return (1.f - e) * __builtin_amdgcn_rcpf(1.f + e);
}
__device__ __forceinline__ float rdlf(float v, int k) {
    return __int_as_float(__builtin_amdgcn_readlane(__float_as_int(v), k));
}
// DPP lane exchange (pure VALU; no LDS pipe)
template <int CTRL>
__device__ __forceinline__ unsigned dppq_u(unsigned v) {
    return (unsigned)__builtin_amdgcn_update_dpp(0, (int)v, CTRL, 0xF, 0xF, true);
}
template <int CTRL>
__device__ __forceinline__ float dppq_f(float v) {
    return __uint_as_float(dppq_u<CTRL>(__float_as_uint(v)));
}
#define DPP_XOR2   0x4E    // quad_perm [2,3,0,1] : partner unit (lane^2)
#define DPP_BODD   0xF5    // quad_perm [1,1,3,3] : broadcast odd lane of pair
#define DPP_BEVN   0xA0    // quad_perm [0,0,2,2] : broadcast even lane of pair
#define DPP_HMIRR  0x141   // row_half_mirror: lane l -> l^7  (quad p -> p^1)
#define DPP_ROR8   0x128   // row rotate 8:    lane l -> l^8  (quad p -> p^2)
#define DPP_MIRR   0x140   // row_mirror:      lane l -> l^15 (quad p -> p^3)

// dup-pair gate-column mapping: lane l -> first col ca, second col ca+64
__device__ __host__ __forceinline__ int col_a(int l) {
    return (l >> 1) + 32 * (l & 1);
}

// ---------------------------------------------------------------------------
// Inline dtype detector (true -> fp32 buffers, false -> bf16 buffers).
// Wave-parallel; every block computes it redundantly (1 load + ballot).
// ---------------------------------------------------------------------------
__device__ __forceinline__ bool detect_f32(const unsigned* __restrict__ bias_w,
                                           int lane) {
    const unsigned u  = bias_w[lane];
    const unsigned lo = u & 0xFFFFu;
    const float vlo = __uint_as_float(lo << 16);
    const float vhi = __uint_as_float(u & 0xFFFF0000u);
    const bool nz_even = (lo != 0u);
    const bool big = !(fabsf(vlo) < 1e6f) || !(fabsf(vhi) < 1e6f);
    const unsigned long long nz = __ballot(nz_even);
    const unsigned long long bg = __ballot(big);
    return (nz == 0ull || bg != 0ull);
}

// ---------------------------------------------------------------------------
// Token z-table, dup-pair permuted, prescaled by log2(e), g-columns by 2x,
// and i-columns (even-lane a-entries) biased by +1 so the scan's rcp gives
// 2*sigma directly:
//   ZK[v][2l]   = log2e * z_x[col_a(l)] + (l even ? 1 : 0)
//   ZK[v][2l+1] = log2e * s * z_x[col_a(l)+64], s=2 for even l (g), 1 (o)
// 8 vocab rows per block: weight regs loaded once, reused 8x.
// ---------------------------------------------------------------------------
#define ZK_RPB 8
__global__ __launch_bounds__(64) void zk_kernel(
    const void* __restrict__ emb, const void* __restrict__ Wk,
    const void* __restrict__ bias, float* __restrict__ ZK)
{
    const int l  = threadIdx.x;
    const int v0 = blockIdx.x * ZK_RPB;
    const bool f32 = detect_f32((const unsigned*)bias, l);
    const int ca = col_a(l), cb = ca + 64;
    const float ba_add = ((l & 1) == 0) ? 1.f : 0.f;     // i-col exp-fold bias
    const float sb = ((l & 1) == 0) ? 2.f * LOG2E : LOG2E;

    float wa[EMB], wb[EMB], ba, bb;
    if (f32) {
        const float* W = (const float*)Wk;
        const float* B = (const float*)bias;
#pragma unroll
        for (int e = 0; e < EMB; ++e) { wa[e] = W[e * G + ca]; wb[e] = W[e * G + cb]; }
        ba = B[ca]; bb = B[cb];
    } else {
        const unsigned short* W = (const unsigned short*)Wk;
        const unsigned short* B = (const unsigned short*)bias;
#pragma unroll
        for (int e = 0; e < EMB; ++e) { wa[e] = bf2f(W[e * G + ca]); wb[e] = bf2f(W[e * G + cb]); }
        ba = bf2f(B[ca]); bb = bf2f(B[cb]);
    }

#pragma unroll
    for (int r = 0; r < ZK_RPB; ++r) {
        const int v = v0 + r;
        float x[EMB];
        if (f32) {
            const float* E = (const float*)emb + (size_t)v * EMB;
#pragma unroll
            for (int e = 0; e < EMB; ++e) x[e] = E[e];
        } else {
            const unsigned short* E = (const unsigned short*)emb + (size_t)v * EMB;
#pragma unroll
            for (int e = 0; e < EMB; ++e) x[e] = bf2f(E[e]);
        }
        float za = ba, zb = bb;
#pragma unroll
        for (int e = 0; e < EMB; ++e) {
            za = fmaf(x[e], wa[e], za);
            zb = fmaf(x[e], wb[e], zb);
        }
        v2f o2;
        o2.x = fmaf(za, LOG2E, ba_add);
        o2.y = zb * sb;
        *(v2f*)(ZK + (size_t)v * G + 2 * l) = o2;
    }
}

// ---------------------------------------------------------------------------
// Scan (dup-pair + MFMA): lane l owns hidden unit j=l>>1, half=l&1.
// h->h chain per step: pack (add, dpp, perm, dpp) -> 8 MFMA with z folded
// into C.x ONLY ({z,0,0,0}: C.x lands exactly in the slot each lane reads;
// zeros are loop-invariant, 1 mov/side/step) -> sel -> exp2 (neg modifier)
// -> add -> rcp (one rcp = 2i even | f odd) -> bevn/bodd dpps -> gT fma ->
// cN fma (cS = -2log2e*c domain) -> exp2 -> add -> rcp -> fma hN.
// token==0 via wave-uniform rare SALU branch. ZERO DS in the chain.
// ---------------------------------------------------------------------------
template <bool F32OUT>
__device__ __forceinline__ void scan_zk_loop(
    const int* __restrict__ trow, const float* __restrict__ ZK,
    void* __restrict__ orow, const short8 (&Bf)[8], int lane)
{
    const bool  h0  = (lane & 1) == 0;          // half 0: (i,g); half 1: (f,o)
    const float Kc  = h0 ? 0.5f : 1.0f;         // rcp add-const for a-side
    const int   oj  = lane >> 1;                // my hidden unit
    const int   g4  = (lane >> 4) & 3;          // which MFMA holds my column
    const bool  u_odd = (lane >> 1) & 1;        // my unit index parity
    const unsigned psel = u_odd ? 0x03020706u : 0x07060302u;  // v_perm selector
    const int   lm  = lane & 15;

    const f32x4 zc = {0.f, 0.f, 0.f, 0.f};
    float h = 0.f, cS = 0.f;                    // cS = -2log2e * c

    // ---- tokens as scalars: one coalesced vector load per 16-chunk,
    //      extracted to SGPRs via readlane ----
    int tva = trow[lm];           // chunk 0
    int tvb = trow[16 + lm];      // chunk 1
    int tc[16], tn[16];
#pragma unroll
    for (int p = 0; p < 16; ++p) tc[p] = __builtin_amdgcn_readlane(tva, p);
#pragma unroll
    for (int p = 0; p < 16; ++p) tn[p] = __builtin_amdgcn_readlane(tvb, p);

    // ---- ZK prefetch ring, distance 8 ----
    v2f pz[8];
#pragma unroll
    for (int d = 0; d < 8; ++d)
        pz[d] = *(const v2f*)(ZK + (size_t)tc[d] * G + 2 * lane);

    for (int cc = 0; cc < TT / 16; ++cc) {
        const int base = cc * 16;
        // issue chunk cc+2 token vector load early (clamped at tail)
        const int nxtc = (cc + 2 < TT / 16) ? (cc + 2) : (TT / 16 - 1);
        const int tvc = trow[nxtc * 16 + lm];
#pragma unroll
        for (int u = 0; u < 16; ++u) {
            const int t = base + u;
            const v2f z = pz[u & 7];
            {   // prefetch z for t+8 (scalar token -> saddr-form load)
                const int ptok = (u + 8 < 16) ? tc[u + 8] : tn[u - 8];
                pz[u & 7] = *(const v2f*)(ZK + (size_t)ptok * G + 2 * lane);
            }

            // C operands: z folded into the .x slot only (slot each lane
            // reads); .y/.z/.w stay loop-invariant zeros (1 mov per side).
            f32x4 Ca = zc; Ca[0] = z.x;
            f32x4 Cb = zc; Cb[0] = z.y;

            // ---- A-frag pack (R2-proven 5-op form): round, partner via
            //      DPP xor2, variable-sel v_perm, 3 static DPP gathers.
            //      Slot q holds pair(p^q); compensated in B-frag k-perm. ----
            const unsigned rh  = __float_as_uint(h) + 0x8000u;   // round-half-up
            const unsigned prt = dppq_u<DPP_XOR2>(rh);           // partner unit
            const unsigned pair = __builtin_amdgcn_perm(prt, rh, psel);
            const unsigned q1 = dppq_u<DPP_HMIRR>(pair);         // pair(p^1)
            const unsigned q2 = dppq_u<DPP_ROR8 >(pair);         // pair(p^2)
            const unsigned q3 = dppq_u<DPP_MIRR >(pair);         // pair(p^3)
            union { unsigned u4[4]; short8 s8; } au;
            au.u4[0] = pair; au.u4[1] = q1; au.u4[2] = q2; au.u4[3] = q3;
            const short8 Af = au.s8;

            // ---- 8 MFMAs.  b-side (deep gate path) issued FIRST; its tail
            //      can start while the a-side MFMAs still occupy the pipe. ----
            f32x4 d4 = __builtin_amdgcn_mfma_f32_16x16x32_bf16(Af, Bf[4], Cb, 0, 0, 0);
            f32x4 d5 = __builtin_amdgcn_mfma_f32_16x16x32_bf16(Af, Bf[5], Cb, 0, 0, 0);
            f32x4 d6 = __builtin_amdgcn_mfma_f32_16x16x32_bf16(Af, Bf[6], Cb, 0, 0, 0);
            f32x4 d7 = __builtin_amdgcn_mfma_f32_16x16x32_bf16(Af, Bf[7], Cb, 0, 0, 0);
            f32x4 d0 = __builtin_amdgcn_mfma_f32_16x16x32_bf16(Af, Bf[0], Ca, 0, 0, 0);
            f32x4 d1 = __builtin_amdgcn_mfma_f32_16x16x32_bf16(Af, Bf[1], Ca, 0, 0, 0);
            f32x4 d2 = __builtin_amdgcn_mfma_f32_16x16x32_bf16(Af, Bf[2], Ca, 0, 0, 0);
            f32x4 d3 = __builtin_amdgcn_mfma_f32_16x16x32_bf16(Af, Bf[3], Ca, 0, 0, 0);

            // my columns (z already included via C.x)
            const float zb = (g4 < 2) ? (g4 == 0 ? d4.x : d5.x)
                                      : (g4 == 2 ? d6.x : d7.x);
            const float za = (g4 < 2) ? (g4 == 0 ? d0.x : d1.x)
                                      : (g4 == 2 ? d2.x : d3.x);

            // one rcp gives 2i (even, Kc=0.5) or f (odd, Kc=1)
            const float exb = __builtin_amdgcn_exp2f(-zb);
            const float exa = __builtin_amdgcn_exp2f(-za);
            const float s2  = __builtin_amdgcn_rcpf(exb + 1.f);  // sig(2zg)|o
            const float r1  = __builtin_amdgcn_rcpf(exa + Kc);
            // bevn distributes over the product: cN = 2i*(-L*g) + f*cS
            const float sE  = dppq_f<DPP_BEVN>(s2);     // sig(2zg) pair-wide
            const float oG  = dppq_f<DPP_BODD>(s2);     // o
            const float gA  = dppq_f<DPP_BEVN>(r1);     // 2i
            const float fO  = dppq_f<DPP_BODD>(r1);     // f
            const float gT  = fmaf(sE, -TWOLOG2E, LOG2E);   // -L*g
            const float fc  = fO * cS;
            float cN  = fmaf(gA, gT, fc);               // -2log2e*c_new

            // h = o*tanh(c) = 2o*rcp(1+e^{-2c}) - o ; e^{-2c} = exp2(cS)
            const float exh = __builtin_amdgcn_exp2f(cN);
            const float rr  = __builtin_amdgcn_rcpf(exh + 1.f);
            const float oo  = oG + oG;                  // off-chain
            float hN  = fmaf(oo, rr, -oG);

            // token==0 is ~0.02%: wave-uniform SALU branch, no on-chain sel
            if (__builtin_expect(tc[u] == 0, 0)) { cN = cS; hN = h; }
            cS = cN; h = hN;

            const int oi = t * HID + oj;     // pair lanes: same addr+data
            if (F32OUT) __builtin_nontemporal_store(h, (float*)orow + oi);
            else        __builtin_nontemporal_store(f2bf(h), (unsigned short*)orow + oi);
        }
        // rotate token chunks (SALU), extract prefetched chunk cc+2
#pragma unroll
        for (int p = 0; p < 16; ++p) tc[p] = tn[p];
#pragma unroll
        for (int p = 0; p < 16; ++p) tn[p] = __builtin_amdgcn_readlane(tvc, p);
    }
}

__global__ __launch_bounds__(64) void scan_zk_kernel(
    const int* __restrict__ tokens, const float* __restrict__ ZK,
    const void* __restrict__ Wr, const void* __restrict__ bias,
    void* __restrict__ out)
{
    const int lane = threadIdx.x, b = blockIdx.x;
    const bool f32 = detect_f32((const unsigned*)bias, lane);

    // B-frags: MFMA q<4 -> first-gate cols ca(16q+n); q>=4 -> cb(16(q-4)+n).
    // Lane holds B[k=(lane>>4)*8+j][n=lane&15], k XOR-permuted per MFMA
    // (j ^ (q<<1)) to absorb the DPP all-gather's pair(p^q) layout; scaled by
    // log2e, and additionally by 2 for g-columns (p>=4, even n).
    short8 Bf[8];
    const int n  = lane & 15;
    const int k0 = (lane >> 4) * 8;
#pragma unroll
    for (int p = 0; p < 8; ++p) {
        const int ell = 16 * (p & 3) + n;
        const int col = (p < 4) ? col_a(ell) : (col_a(ell) + 64);
        const int jx  = (p & 3) << 1;         // k-pair XOR permutation
        const float sc = (p >= 4 && (n & 1) == 0) ? 2.f * LOG2E : LOG2E;
        short el[8];
        if (f32) {
            const float* W = (const float*)Wr;
#pragma unroll
            for (int j = 0; j < 8; ++j)
                el[j] = (short)f2bf(W[(k0 + (j ^ jx)) * G + col] * sc);
        } else {
            const unsigned short* W = (const unsigned short*)Wr;
#pragma unroll
            for (int j = 0; j < 8; ++j)
                el[j] = (short)f2bf(bf2f(W[(k0 + (j ^ jx)) * G + col]) * sc);
        }
        short8 s;
#pragma unroll
        for (int j = 0; j < 8; ++j) s[j] = el[j];
        Bf[p] = s;
    }

    const int* trow = tokens + (size_t)b * TT;
    if (f32) scan_zk_loop<true >(trow, ZK, (char*)out + (size_t)b * TT * HID * 4, Bf, lane);
    else     scan_zk_loop<false>(trow, ZK, (char*)out + (size_t)b * TT * HID * 2, Bf, lane);
}

// ---------------------------------------------------------------------------
// Fallback (workspace too small): proven R2/R3 fused kernel (natural units).
// ---------------------------------------------------------------------------
template <bool F32>
__device__ __forceinline__ void row_load(const void* emb, int tok, uint4* r) {
    if (F32) { const uint4* p = (const uint4*)((const float*)emb + (size_t)tok*EMB);
               r[0]=p[0]; r[1]=p[1]; r[2]=p[2]; r[3]=p[3]; }
    else     { const uint4* p = (const uint4*)((const unsigned short*)emb + (size_t)tok*EMB);
               r[0]=p[0]; r[1]=p[1]; }
}
template <bool F32>
__device__ __forceinline__ void row_unpack(const uint4* r, float* x) {
    if (F32) {
        const unsigned w[16] = {r[0].x,r[0].y,r[0].z,r[0].w, r[1].x,r[1].y,r[1].z,r[1].w,
                                r[2].x,r[2].y,r[2].z,r[2].w, r[3].x,r[3].y,r[3].z,r[3].w};
#pragma unroll
        for (int e = 0; e < 16; ++e) x[e] = __uint_as_float(w[e]);
    } else {
        const unsigned w[8] = {r[0].x,r[0].y,r[0].z,r[0].w, r[1].x,r[1].y,r[1].z,r[1].w};
#pragma unroll
        for (int q = 0; q < 8; ++q) {
            x[2*q]   = __uint_as_float(w[q] << 16);
            x[2*q+1] = __uint_as_float(w[q] & 0xFFFF0000u);
        }
    }
}

template <bool F32>
__device__ __forceinline__ void scan_fused_loop(
    const int* __restrict__ trow, const void* __restrict__ emb, void* orow,
    const float (&wka)[EMB], const float (&wkb)[EMB],
    const float (&wra)[HID], const float (&wrb)[HID],
    float za0, float zb0, const int* tl, int lane)
{
    const bool  lo  = lane < HID;
    const float zsc = lo ? 2.f : 1.f, gm = lo ? 2.f : 1.f, ga = lo ? -1.f : 0.f;
    float h = 0.f, c = 0.f;
    uint4 praw[2][4];
    row_load<F32>(emb, trow[0], praw[0]);
    row_load<F32>(emb, trow[1], praw[1]);

    for (int tt = 0; tt < TT; tt += 2) {
#pragma unroll
        for (int u = 0; u < 2; ++u) {
            const int t = tt + u;
            float x[EMB];
            row_unpack<F32>(praw[u], x);
            int tn = t + 2; tn = tn > TT - 1 ? TT - 1 : tn;
            row_load<F32>(emb, tl[tn], praw[u]);
            float za = za0, zb = zb0;
#pragma unroll
            for (int e = 0; e < EMB; ++e) { za = fmaf(x[e], wka[e], za); zb = fmaf(x[e], wkb[e], zb); }
#pragma unroll
            for (int k = 0; k < HID; ++k) {
                const float hk = rdlf(h, k);
                za = fmaf(hk, wra[k], za);
                zb = fmaf(hk, wrb[k], zb);
            }
            const float a1 = sigm(za);
            const float s2 = sigm(zb * zsc);
            const float a2 = fmaf(s2, gm, ga);
            const float x1 = __shfl_xor(a1, 32);
            const float x2 = __shfl_xor(a2, 32);
            const float iV = lo ? a1 : x1, fV = lo ? x1 : a1;
            const float gV = lo ? a2 : x2, oV = lo ? x2 : a2;
            const float cN = fmaf(fV, c, iV * gV);
            const float hN = oV * tanh_f(cN);
            const bool  m  = tl[t] != 0;
            c = m ? cN : c;
            h = m ? hN : h;
            const int oi = t * HID + (lane & (HID - 1));
            if (F32) ((float*)orow)[oi] = h;
            else     ((unsigned short*)orow)[oi] = f2bf(h);
        }
    }
}

__global__ __launch_bounds__(64) void scan_fused_kernel(
    const int* __restrict__ tokens, const void* __restrict__ emb,
    const void* __restrict__ Wk, const void* __restrict__ Wr,
    const void* __restrict__ bias, void* __restrict__ out)
{
    __shared__ int tl[TT];
    const int lane = threadIdx.x, b = blockIdx.x;
    const bool f32 = detect_f32((const unsigned*)bias, lane);
    const int* trow = tokens + (size_t)b * TT;
    for (int t = lane; t < TT; t += 64) tl[t] = trow[t];

    float wka[EMB], wkb[EMB], wra[HID], wrb[HID], za0, zb0;
    if (f32) {
        const float* WK = (const float*)Wk; const float* WR = (const float*)Wr;
        const float* B  = (const float*)bias;
#pragma unroll
        for (int e = 0; e < EMB; ++e) { wka[e] = WK[e*G + lane]; wkb[e] = WK[e*G + lane + 64]; }
#pragma unroll
        for (int k = 0; k < HID; ++k) { wra[k] = WR[k*G + lane]; wrb[k] = WR[k*G + lane + 64]; }
        za0 = B[lane]; zb0 = B[lane + 64];
    } else {
        const unsigned short* WK = (const unsigned short*)Wk;
        const unsigned short* WR = (const unsigned short*)Wr;
        const unsigned short* B  = (const unsigned short*)bias;
#pragma unroll
        for (int e = 0; e < EMB; ++e) { wka[e] = bf2f(WK[e*G + lane]); wkb[e] = bf2f(WK[e*G + lane + 64]); }
#pragma unroll
        for (int k = 0; k < HID; ++k) { wra[k] = bf2f(WR[k*G + lane]); wrb[k] = bf2f(WR[k*G + lane + 64]); }
        za0 = bf2f(B[lane]); zb0 = bf2f(B[lane + 64]);
    }
    __syncthreads();

    if (f32) scan_fused_loop<true >(trow, emb, (char*)out + (size_t)b*TT*HID*4,
                                    wka, wkb, wra, wrb, za0, zb0, tl, lane);
    else     scan_fused_loop<false>(trow, emb, (char*)out + (size_t)b*TT*HID*2,
                                    wka, wkb, wra, wrb, za0, zb0, tl, lane);
}

// ---------------------------------------------------------------------------
extern "C" void kernel_launch(void* const* d_in, const int* in_sizes, int n_in,
                              void* d_out, int out_size, void* d_ws, size_t ws_size,
                              hipStream_t stream) {
    const int*  tokens = (const int*)d_in[0];
    const void* emb    = d_in[1];
    const void* Wk     = d_in[2];
    const void* Wr     = d_in[3];
    const void* bias   = d_in[4];

    const size_t zk_off   = 256;
    const size_t zk_bytes = (size_t)VOC * G * sizeof(float);   // 2.56 MB

    if (ws_size >= zk_off + zk_bytes) {
        float* ZK = (float*)((char*)d_ws + zk_off);
        zk_kernel<<<VOC / ZK_RPB, 64, 0, stream>>>(emb, Wk, bias, ZK);
        scan_zk_kernel<<<BB, 64, 0, stream>>>(tokens, ZK, Wr, bias, d_out);
    } else {
        scan_fused_kernel<<<BB, 64, 0, stream>>>(tokens, emb, Wk, Wr, bias, d_out);
    }
}